// Round 1
// baseline (954.490 us; speedup 1.0000x reference)
//
#include <hip/hip_runtime.h>
#include <hip/hip_bf16.h>
#include <math.h>

// Problem constants (from the reference file; RECORD_LEN is a module constant).
#define C_DIM 256
#define W_DIM 64
#define H_DIM 192
#define WH (W_DIM * H_DIM)          // 12288 spatial positions
#define NGROUPS 8

// offsets = cumsum([0,5,3,4,2,5,3,4,2])
__constant__ const int k_off[NGROUPS] = {0, 5, 8, 12, 14, 19, 22, 26};

// One thread per spatial position n. Pass 1: gram matrix over L record-vectors
// (dim C=256, stride WH in memory -> loads coalesced across n). Softmax row 0.
// Pass 2: context = sum_m p0[m] * x[m,c,n], streamed back out.
// WRITE_ATTN: also emit the full LxL softmax map (last group only).
template <int L, bool WRITE_ATTN>
__global__ __launch_bounds__(256) void att_group_kernel(
    const float* __restrict__ xg,   // group base: x + off*C*WH
    float* __restrict__ out,        // out0 + g*C*WH  (C, WH)
    float* __restrict__ attn_out)   // (L, L, WH) or nullptr
{
    const int n = blockIdx.x * 256 + threadIdx.x;   // 48 blocks * 256 = 12288

    // ---- Pass 1: upper-triangle gram accumulators ----
    constexpr int NTRI = L * (L + 1) / 2;
    float s[NTRI];
#pragma unroll
    for (int i = 0; i < NTRI; ++i) s[i] = 0.0f;

#pragma unroll 4
    for (int c = 0; c < C_DIM; ++c) {
        float v[L];
#pragma unroll
        for (int l = 0; l < L; ++l)
            v[l] = xg[(l * C_DIM + c) * WH + n];
        int idx = 0;
#pragma unroll
        for (int l = 0; l < L; ++l)
#pragma unroll
            for (int m = l; m < L; ++m)
                s[idx++] += v[l] * v[m];
    }

    const float scale = 0.0625f;   // 1/sqrt(256)

    // ---- Softmax of row 0 (upper triangle row 0 == full row 0) ----
    float p0[L];
    float mx = -INFINITY;
#pragma unroll
    for (int m = 0; m < L; ++m) {
        p0[m] = s[m] * scale;
        mx = fmaxf(mx, p0[m]);
    }
    float sum = 0.0f;
#pragma unroll
    for (int m = 0; m < L; ++m) {
        p0[m] = __expf(p0[m] - mx);
        sum += p0[m];
    }
    const float inv = 1.0f / sum;
#pragma unroll
    for (int m = 0; m < L; ++m) p0[m] *= inv;

    // ---- Optional: full attention map (transpose(1,2,0): [l][m][n]) ----
    if constexpr (WRITE_ATTN) {
        float g[L][L];
        int idx = 0;
#pragma unroll
        for (int l = 0; l < L; ++l)
#pragma unroll
            for (int m = l; m < L; ++m) {
                const float v = s[idx++] * scale;
                g[l][m] = v;
                g[m][l] = v;
            }
#pragma unroll
        for (int l = 0; l < L; ++l) {
            float mx2 = -INFINITY;
#pragma unroll
            for (int m = 0; m < L; ++m) mx2 = fmaxf(mx2, g[l][m]);
            float e[L];
            float sm = 0.0f;
#pragma unroll
            for (int m = 0; m < L; ++m) {
                e[m] = __expf(g[l][m] - mx2);
                sm += e[m];
            }
            const float iv = 1.0f / sm;
#pragma unroll
            for (int m = 0; m < L; ++m)
                attn_out[(l * L + m) * WH + n] = e[m] * iv;
        }
    }

    // ---- Pass 2: context for row 0, streamed store ----
#pragma unroll 2
    for (int c = 0; c < C_DIM; ++c) {
        float acc = 0.0f;
#pragma unroll
        for (int m = 0; m < L; ++m)
            acc += p0[m] * xg[(m * C_DIM + c) * WH + n];
        out[c * WH + n] = acc;
    }
}

extern "C" void kernel_launch(void* const* d_in, const int* in_sizes, int n_in,
                              void* d_out, int out_size, void* d_ws, size_t ws_size,
                              hipStream_t stream) {
    const float* x = (const float*)d_in[0];
    float* out0 = (float*)d_out;                      // (8, C, W, H)
    float* attn = out0 + (size_t)NGROUPS * C_DIM * WH; // (2, 2, W, H), last group

    static const int offs[NGROUPS] = {0, 5, 8, 12, 14, 19, 22, 26};
    static const int lens[NGROUPS] = {5, 3, 4, 2, 5, 3, 4, 2};

    const dim3 grid(WH / 256);   // 48
    const dim3 block(256);

    for (int g = 0; g < NGROUPS; ++g) {
        const float* xg = x + (size_t)offs[g] * C_DIM * WH;
        float* og = out0 + (size_t)g * C_DIM * WH;
        const bool is_last = (g == NGROUPS - 1);
        switch (lens[g]) {
            case 5:
                att_group_kernel<5, false><<<grid, block, 0, stream>>>(xg, og, nullptr);
                break;
            case 4:
                att_group_kernel<4, false><<<grid, block, 0, stream>>>(xg, og, nullptr);
                break;
            case 3:
                att_group_kernel<3, false><<<grid, block, 0, stream>>>(xg, og, nullptr);
                break;
            case 2:
                if (is_last)
                    att_group_kernel<2, true><<<grid, block, 0, stream>>>(xg, og, attn);
                else
                    att_group_kernel<2, false><<<grid, block, 0, stream>>>(xg, og, nullptr);
                break;
        }
    }
}

// Round 2
// 563.216 us; speedup vs baseline: 1.6947x; 1.6947x over previous
//
#include <hip/hip_runtime.h>
#include <hip/hip_bf16.h>
#include <math.h>

// Problem constants (from the reference file; RECORD_LEN is a module constant).
#define C_DIM 256
#define W_DIM 64
#define H_DIM 192
#define WH (W_DIM * H_DIM)          // 12288 spatial positions
#define NGROUPS 8
#define BLOCKS_PER_GROUP (WH / 256) // 48

// One thread per (group, spatial position n). Pass 1: gram matrix over L
// record-vectors (dim C=256, stride WH -> loads coalesced across n).
// Softmax row 0. Pass 2: context = sum_m p0[m] * x[m,c,n], streamed out.
// WRITE_ATTN: also emit the full LxL softmax map (last group only).
template <int L, bool WRITE_ATTN>
__device__ __forceinline__ void att_group_body(
    const float* __restrict__ xg,   // group base: x + off*C*WH
    float* __restrict__ out,        // out0 + g*C*WH  (C, WH)
    float* __restrict__ attn_out,   // (L, L, WH) or nullptr
    int n)
{
    // ---- Pass 1: upper-triangle gram accumulators ----
    constexpr int NTRI = L * (L + 1) / 2;
    float s[NTRI];
#pragma unroll
    for (int i = 0; i < NTRI; ++i) s[i] = 0.0f;

#pragma unroll 4
    for (int c = 0; c < C_DIM; ++c) {
        float v[L];
#pragma unroll
        for (int l = 0; l < L; ++l)
            v[l] = xg[(l * C_DIM + c) * WH + n];
        int idx = 0;
#pragma unroll
        for (int l = 0; l < L; ++l)
#pragma unroll
            for (int m = l; m < L; ++m)
                s[idx++] += v[l] * v[m];
    }

    const float scale = 0.0625f;   // 1/sqrt(256)

    // ---- Softmax of row 0 (upper triangle row 0 == full row 0) ----
    float p0[L];
    float mx = -INFINITY;
#pragma unroll
    for (int m = 0; m < L; ++m) {
        p0[m] = s[m] * scale;
        mx = fmaxf(mx, p0[m]);
    }
    float sum = 0.0f;
#pragma unroll
    for (int m = 0; m < L; ++m) {
        p0[m] = __expf(p0[m] - mx);
        sum += p0[m];
    }
    const float inv = 1.0f / sum;
#pragma unroll
    for (int m = 0; m < L; ++m) p0[m] *= inv;

    // ---- Optional: full attention map (transpose(1,2,0): [l][m][n]) ----
    if constexpr (WRITE_ATTN) {
        float g[L][L];
        int idx = 0;
#pragma unroll
        for (int l = 0; l < L; ++l)
#pragma unroll
            for (int m = l; m < L; ++m) {
                const float v = s[idx++] * scale;
                g[l][m] = v;
                g[m][l] = v;
            }
#pragma unroll
        for (int l = 0; l < L; ++l) {
            float mx2 = -INFINITY;
#pragma unroll
            for (int m = 0; m < L; ++m) mx2 = fmaxf(mx2, g[l][m]);
            float e[L];
            float sm = 0.0f;
#pragma unroll
            for (int m = 0; m < L; ++m) {
                e[m] = __expf(g[l][m] - mx2);
                sm += e[m];
            }
            const float iv = 1.0f / sm;
#pragma unroll
            for (int m = 0; m < L; ++m)
                attn_out[(l * L + m) * WH + n] = e[m] * iv;
        }
    }

    // ---- Pass 2: context for row 0, streamed store ----
#pragma unroll 4
    for (int c = 0; c < C_DIM; ++c) {
        float acc = 0.0f;
#pragma unroll
        for (int m = 0; m < L; ++m)
            acc += p0[m] * xg[(m * C_DIM + c) * WH + n];
        out[c * WH + n] = acc;
    }
}

// Single fused launch: 8 groups x 48 blocks = 384 blocks = 1536 waves
// (6 waves/CU -> enough MLP to saturate HBM; the per-group version had
// only 0.75 waves/CU and ran at 13% of peak BW).
__global__ __launch_bounds__(256) void att_fused_kernel(
    const float* __restrict__ x,
    float* __restrict__ out0,
    float* __restrict__ attn)
{
    const int b = blockIdx.x;
    const int g = b / BLOCKS_PER_GROUP;            // block-uniform
    const int bn = b - g * BLOCKS_PER_GROUP;
    const int n = bn * 256 + threadIdx.x;

    const int offs[NGROUPS] = {0, 5, 8, 12, 14, 19, 22, 26};
    const int lens[NGROUPS] = {5, 3, 4, 2, 5, 3, 4, 2};

    const float* xg = x + (size_t)offs[g] * C_DIM * WH;
    float* og = out0 + (size_t)g * C_DIM * WH;

    switch (lens[g]) {   // block-uniform branch -> no divergence
        case 5: att_group_body<5, false>(xg, og, nullptr, n); break;
        case 4: att_group_body<4, false>(xg, og, nullptr, n); break;
        case 3: att_group_body<3, false>(xg, og, nullptr, n); break;
        case 2:
            if (g == NGROUPS - 1)
                att_group_body<2, true>(xg, og, attn, n);
            else
                att_group_body<2, false>(xg, og, nullptr, n);
            break;
    }
}

extern "C" void kernel_launch(void* const* d_in, const int* in_sizes, int n_in,
                              void* d_out, int out_size, void* d_ws, size_t ws_size,
                              hipStream_t stream) {
    const float* x = (const float*)d_in[0];
    float* out0 = (float*)d_out;                        // (8, C, W, H)
    float* attn = out0 + (size_t)NGROUPS * C_DIM * WH;  // (2, 2, W, H), last group

    const dim3 grid(NGROUPS * BLOCKS_PER_GROUP);   // 384
    const dim3 block(256);
    att_fused_kernel<<<grid, block, 0, stream>>>(x, out0, attn);
}